// Round 1
// 1425.998 us; speedup vs baseline: 1.0627x; 1.0627x over previous
//
#include <hip/hip_runtime.h>
#include <hip/hip_bf16.h>

#define EDGES   519840
#define NGRID   519840
#define NMESH   5882

typedef short s8v __attribute__((ext_vector_type(8)));
typedef float f4v __attribute__((ext_vector_type(4)));

// ---- ws layout ----
// packed weights (bf16 shorts), element offsets:
#define OFF_ENC1   0        // 8 ksteps * 16 ntiles * 64 * 8 = 65536 el ([Wr|W1] 256x256)
#define OFF_ENCW2  65536    // 4*8*64*8  = 16384 el (128x128)
#define OFF_EM1    81920    // 5*9*64*8  = 23040 el (160x144: W1eff|res cols, bias row k=130)
#define OFF_N11    104960   // 5*8*64*8  = 20480 el (160x128, bias row k=130)
#define OFF_N12    125440   // 4*9*64*8  = 18432 el (128x144)
#define PACK_EL    143872
#define GSUM_BYTE_OFF  (PACK_EL*2)            // 287744
#define GSUM_BYTES     (NMESH*130*4)          // 3058640
#define CNT_BYTE_OFF   (GSUM_BYTE_OFF + GSUM_BYTES)
#define CNT_BYTES      (NMESH*4)

__device__ __forceinline__ float b2f(short s) {
  unsigned int u = ((unsigned int)(unsigned short)s) << 16;
  float f; __builtin_memcpy(&f, &u, 4); return f;
}
__device__ __forceinline__ short f2b(float f) {
  __hip_bfloat16 h = __float2bfloat16(f);   // RNE
  short s; __builtin_memcpy(&s, &h, 2); return s;
}

// ---------------- weight pack kernel (fp32 -> bf16, MFMA B layout) ----------------
struct PArgs {
  const float *enc_Wr, *enc_W1, *enc_W2;
  const float *em_Wr, *em_W1, *em_b1, *em_br;
  const float *n1_W1, *n1_b1, *n1_W2;
  short* dst;
};

__global__ __launch_bounds__(256) void kPack(PArgs p) {
  int g = blockIdx.x * 256 + threadIdx.x;
  if (g >= 17984) return;
  short* dst = p.dst;
  if (g < 8192) {                       // enc combined [Wr|W1], K=256, NT=16
    int s = g >> 10; int rem = g & 1023; int t = rem >> 6; int l = rem & 63;
    int qq = l >> 4, n = (t << 4) + (l & 15);
    s8v v;
    #pragma unroll
    for (int j = 0; j < 8; ++j) {
      int k = s*32 + qq*8 + j;
      v[j] = (n < 128) ? f2b(p.enc_Wr[k*128 + n]) : f2b(p.enc_W1[k*128 + (n-128)]);
    }
    ((s8v*)(dst + OFF_ENC1))[g] = v;
  } else if (g < 10240) {               // enc_W2, K=128, NT=8
    int g2 = g - 8192;
    int s = g2 >> 9; int t = (g2 >> 6) & 7; int l = g2 & 63;
    int qq = l >> 4, n = (t << 4) + (l & 15);
    s8v v;
    #pragma unroll
    for (int j = 0; j < 8; ++j) { int k = s*32 + qq*8 + j; v[j] = f2b(p.enc_W2[k*128 + n]); }
    ((s8v*)(dst + OFF_ENCW2))[g2] = v;
  } else if (g < 13120) {               // em1: KP=160, NT=9 (cols 128..129 = residual Wr)
    int g3 = g - 10240;
    int s = g3 / 576; int rem = g3 - s*576; int t = rem >> 6; int l = rem & 63;
    int qq = l >> 4, n = (t << 4) + (l & 15);
    s8v v;
    #pragma unroll
    for (int j = 0; j < 8; ++j) {
      int k = s*32 + qq*8 + j;
      float val = 0.f;
      if (n < 128) {
        if (k < 128)        val = p.em_W1[k*128 + n];
        else if (k < 130)   val = p.em_W1[(128 + k)*128 + n];   // rows 256,257 (edge_attr)
        else if (k == 130)  val = p.em_b1[n];                   // bias fold (A col130 = 1)
      } else if (n < 130) {
        int h = n - 128;
        if (k < 128)        val = p.em_Wr[k*2 + h];
        else if (k < 130)   val = p.em_Wr[(128 + k)*2 + h];
        else if (k == 130)  val = p.em_br[h];
      }
      v[j] = f2b(val);
    }
    ((s8v*)(dst + OFF_EM1))[g3] = v;
  } else if (g < 15680) {               // n1_W1: KP=160, NT=8
    int g4 = g - 13120;
    int s = g4 >> 9; int t = (g4 >> 6) & 7; int l = g4 & 63;
    int qq = l >> 4, n = (t << 4) + (l & 15);
    s8v v;
    #pragma unroll
    for (int j = 0; j < 8; ++j) {
      int k = s*32 + qq*8 + j;
      float val = 0.f;
      if (k < 130)       val = p.n1_W1[k*128 + n];
      else if (k == 130) val = p.n1_b1[n];
      v[j] = f2b(val);
    }
    ((s8v*)(dst + OFF_N11))[g4] = v;
  } else {                              // n1_W2: K=128, NT=9 (N padded 130->144)
    int g5 = g - 15680;
    int s = g5 / 576; int rem = g5 - s*576; int t = rem >> 6; int l = rem & 63;
    int qq = l >> 4, n = (t << 4) + (l & 15);
    s8v v;
    #pragma unroll
    for (int j = 0; j < 8; ++j) {
      int k = s*32 + qq*8 + j;
      v[j] = (n < 130) ? f2b(p.n1_W2[k*130 + n]) : (short)0;
    }
    ((s8v*)(dst + OFF_N12))[g5] = v;
  }
}

// ---------------- generic MFMA tile loop ----------------
template<int KS, int MAXT>
__device__ __forceinline__ void run_gemm(const short* A, int strideA,
                                         const short* Bpack, int ntp,
                                         const int* tiles, int nt, int lane,
                                         f4v acc[][MAXT]) {
  const int m = lane & 15, qq = lane >> 4;
  const s8v* Bp = (const s8v*)Bpack;
  #pragma unroll
  for (int s = 0; s < KS; ++s) {
    s8v af[4];
    #pragma unroll
    for (int mt = 0; mt < 4; ++mt)
      af[mt] = *(const s8v*)(A + (mt*16 + m)*strideA + s*32 + qq*8);
    #pragma unroll
    for (int ti = 0; ti < MAXT; ++ti) {
      if (ti < nt) {
        s8v bf = Bp[(s*ntp + tiles[ti])*64 + lane];
        #pragma unroll
        for (int mt = 0; mt < 4; ++mt)
          acc[mt][ti] = __builtin_amdgcn_mfma_f32_16x16x32_bf16(af[mt], bf, acc[mt][ti], 0, 0, 0);
      }
    }
  }
}

// ---------------- fused per-edge kernel ----------------
struct AArgs {
  const float *x, *eattr;
  const int   *eidx;
  const float *enc_br, *enc_b1, *enc_b2, *enc_g, *enc_bn;
  const float *em_W2, *em_b2, *em_g, *em_bn;
  const float *n1_b2, *n1_g, *n1_bn;
  const short *Penc1, *PencW2, *Pem1, *Pn11, *Pn12;
  float *gsum, *cnt;
};

// LDS budget: 21504 (ldsX) + 17408 (ldsH) + 2048 (ldsD) = 40960 B -> 4 blocks/CU.
__global__ __launch_bounds__(256, 4) void kA(AArgs a) {
  __shared__ __align__(16) short ldsX[64*168];  // X half-tile [64][136]; later xh [64][168]
                                                // per-row hole cols 160..163: {mu, rsig}
  __shared__ __align__(16) short ldsH[64*136];  // hidden buffer (all FFN hiddens)
  __shared__ __align__(16) float ldsD[512];     // rowred[512]  OR  vbuf[0..127]+part2[128..383]

  float* const rowred = ldsD;
  float* const vbuf   = ldsD;
  float* const part2  = ldsD + 128;

  const int tid  = threadIdx.x;
  const int lane = tid & 63;
  const int w    = tid >> 6;
  const int m    = lane & 15;
  const int q    = lane >> 4;
  const long row0 = (long)blockIdx.x * 64;

  // per-lane segment id for edge (row0+lane); -1 when out of range (kept in reg, bcast via shfl)
  int segr = -1;
  if (row0 + lane < EDGES) segr = a.eidx[EDGES + row0 + lane] - NGRID;

  float ea0 = 0.f, ea1 = 0.f;
  if (tid < 64 && segr >= 0) {
    atomicAdd(&a.cnt[segr], 1.0f);
    ea0 = a.eattr[(row0 + tid)*2];
    ea1 = a.eattr[(row0 + tid)*2 + 1];
  }

  f4v acc1[4][4];
  const f4v fz = {0.f,0.f,0.f,0.f};
  #pragma unroll
  for (int mt = 0; mt < 4; ++mt)
    #pragma unroll
    for (int nt = 0; nt < 4; ++nt) acc1[mt][nt] = fz;

  // wave w owns R-tiles {2w,2w+1} (cols 32w..32w+31) and H-tiles {8+2w,9+2w}:
  // residual stays in registers (same C-fragment mapping as stage-2 output tiles).
  const int tiles1[4] = {2*w, 2*w+1, 8+2*w, 9+2*w};

  // ---- stage 1: [R | Hpre] = X @ [enc_Wr | enc_W1], K=256 split in two 128-col halves ----
  #pragma unroll
  for (int half = 0; half < 2; ++half) {
    if (half) __syncthreads();          // half-0 LDS reads done before restage
    for (int i = tid; i < 64*16; i += 256) {
      int r = i >> 4, c = (i & 15) << 3;
      s8v v = {0,0,0,0,0,0,0,0};
      if (row0 + r < EDGES) {
        const float* xr = a.x + (row0 + r)*256 + half*128 + c;
        float4 u0 = *(const float4*)(xr);
        float4 u1 = *(const float4*)(xr + 4);
        v[0]=f2b(u0.x); v[1]=f2b(u0.y); v[2]=f2b(u0.z); v[3]=f2b(u0.w);
        v[4]=f2b(u1.x); v[5]=f2b(u1.y); v[6]=f2b(u1.z); v[7]=f2b(u1.w);
      }
      *(s8v*)(ldsX + r*136 + c) = v;
    }
    __syncthreads();
    run_gemm<4,4>(ldsX, 136, a.Penc1 + half*(4*16*64*8), 16, tiles1, 4, lane, acc1);
  }

  // H tiles -> ldsH with ReLU + b1 (wave w covers cols 32w..32w+31)
  #pragma unroll
  for (int ti = 2; ti < 4; ++ti) {
    int hc = (tiles1[ti] - 8)*16 + m;
    float bias = a.enc_b1[hc];
    #pragma unroll
    for (int mt = 0; mt < 4; ++mt)
      #pragma unroll
      for (int r = 0; r < 4; ++r)
        ldsH[(mt*16 + q*4 + r)*136 + hc] = f2b(fmaxf(acc1[mt][ti][r] + bias, 0.f));
  }
  __syncthreads();

  // ---- stage 2: D2 = H1 @ enc_W2 ; S = R + D2 + br + b2 (all in regs) ----
  f4v acc2[4][2];
  #pragma unroll
  for (int mt = 0; mt < 4; ++mt) { acc2[mt][0] = fz; acc2[mt][1] = fz; }
  {
    int tiles[2] = {2*w, 2*w+1};
    run_gemm<4,2>(ldsH, 136, a.PencW2, 8, tiles, 2, lane, acc2);
  }
  #pragma unroll
  for (int nt = 0; nt < 2; ++nt) {
    int col = (2*w + nt)*16 + m;
    float bb = a.enc_br[col] + a.enc_b2[col];
    #pragma unroll
    for (int mt = 0; mt < 4; ++mt)
      #pragma unroll
      for (int r = 0; r < 4; ++r)
        acc2[mt][nt][r] += acc1[mt][nt][r] + bb;
  }

  // ---- LN1 over 128 dims ----
  {
    float sA[4][4], qA[4][4];
    #pragma unroll
    for (int mt = 0; mt < 4; ++mt)
      #pragma unroll
      for (int r = 0; r < 4; ++r) {
        float s = 0.f, ss = 0.f;
        #pragma unroll
        for (int nt = 0; nt < 2; ++nt) { float v = acc2[mt][nt][r]; s += v; ss += v*v; }
        sA[mt][r] = s; qA[mt][r] = ss;
      }
    #pragma unroll
    for (int mask = 1; mask <= 8; mask <<= 1)
      #pragma unroll
      for (int mt = 0; mt < 4; ++mt)
        #pragma unroll
        for (int r = 0; r < 4; ++r) {
          sA[mt][r] += __shfl_xor(sA[mt][r], mask);
          qA[mt][r] += __shfl_xor(qA[mt][r], mask);
        }
    if (m == 0) {
      #pragma unroll
      for (int mt = 0; mt < 4; ++mt)
        #pragma unroll
        for (int r = 0; r < 4; ++r) {
          int row = mt*16 + q*4 + r;
          rowred[(row*4 + w)*2]     = sA[mt][r];
          rowred[(row*4 + w)*2 + 1] = qA[mt][r];
        }
    }
  }
  __syncthreads();
  if (tid < 64) {
    float s = 0.f, ss = 0.f;
    #pragma unroll
    for (int ww = 0; ww < 4; ++ww) { s += rowred[(tid*4+ww)*2]; ss += rowred[(tid*4+ww)*2+1]; }
    float mu = s * (1.f/128.f);
    float var = ss * (1.f/128.f) - mu*mu;
    float* mv = (float*)(ldsX + tid*168 + 160);
    mv[0] = mu; mv[1] = rsqrtf(var + 1e-5f);
  }
  __syncthreads();

  // write x_hat (bf16) into ldsX as [64][168] + [ea | 1.0 | zeros] extension to K=160
  short* const xh = ldsX;
  #pragma unroll
  for (int nt = 0; nt < 2; ++nt) {
    int col = (2*w + nt)*16 + m;
    float gv = a.enc_g[col], bv = a.enc_bn[col];
    #pragma unroll
    for (int mt = 0; mt < 4; ++mt)
      #pragma unroll
      for (int r = 0; r < 4; ++r) {
        int row = mt*16 + q*4 + r;
        const float* mv = (const float*)(ldsX + row*168 + 160);
        xh[row*168 + col] = f2b((acc2[mt][nt][r] - mv[0])*mv[1]*gv + bv);
      }
  }
  if (tid < 64) {
    xh[tid*168 + 128] = f2b(ea0);
    xh[tid*168 + 129] = f2b(ea1);
    xh[tid*168 + 130] = (short)0x3f80;   // bf16 1.0 (bias fold column)
    #pragma unroll
    for (int c = 131; c < 160; ++c) xh[tid*168 + c] = 0;
  }
  __syncthreads();

  // ---- em: hidden (+ residual cols 128..129) = xh160 @ Pem1 ----
  int tiles3[3] = {w, w+4, w+8};
  const int nt3 = (w == 0) ? 3 : 2;
  f4v acc3[4][3];
  #pragma unroll
  for (int mt = 0; mt < 4; ++mt) { acc3[mt][0]=fz; acc3[mt][1]=fz; acc3[mt][2]=fz; }
  run_gemm<5,3>(xh, 168, a.Pem1, 9, tiles3, nt3, lane, acc3);
  #pragma unroll
  for (int ti = 0; ti < 3; ++ti) {
    if (ti < nt3) {
      int col = tiles3[ti]*16 + m;
      if (col < 128) {
        #pragma unroll
        for (int mt = 0; mt < 4; ++mt)
          #pragma unroll
          for (int r = 0; r < 4; ++r) {
            int row = mt*16 + q*4 + r;
            ldsH[row*136 + col] = f2b(fmaxf(acc3[mt][ti][r], 0.f));
          }
      } else if (col < 130) {
        #pragma unroll
        for (int mt = 0; mt < 4; ++mt)
          #pragma unroll
          for (int r = 0; r < 4; ++r) {
            int row = mt*16 + q*4 + r;
            vbuf[row*2 + (col - 128)] = acc3[mt][ti][r];   // residual (br folded)
          }
      }
    }
  }
  __syncthreads();

  // em second projection (128 -> 2) on VALU, fp32 weights
  {
    int r = tid >> 2, p = tid & 3, h = p & 1, kh = p >> 1;
    float s2 = 0.f;
    const short* hb = ldsH + r*136 + kh*64;
    const float* w2 = a.em_W2 + kh*128 + h;   // em_W2[(kh*64+k)*2 + h]
    #pragma unroll 8
    for (int k = 0; k < 64; ++k) s2 += b2f(hb[k]) * w2[2*k];
    part2[tid] = s2;
  }
  __syncthreads();
  if (tid < 128) {
    int r = tid >> 1, h = tid & 1;
    vbuf[tid] = vbuf[tid] + part2[r*4 + h] + part2[r*4 + 2 + h] + a.em_b2[h];
  }
  __syncthreads();
  if (tid < 64) {    // LN over 2 dims, closed form; e = ... + edge_attr
    float v0 = vbuf[2*tid], v1 = vbuf[2*tid+1];
    float d = 0.5f*(v0 - v1);
    float rsg = rsqrtf(d*d + 1e-5f);
    float e0 =  d*rsg*a.em_g[0] + a.em_bn[0] + ea0;
    float e1 = -d*rsg*a.em_g[1] + a.em_bn[1] + ea1;
    xh[tid*168 + 128] = f2b(e0);
    xh[tid*168 + 129] = f2b(e1);
  }
  __syncthreads();

  // ---- n1 hidden: xh160 @ Pn11 ----
  f4v acc4[4][2];
  #pragma unroll
  for (int mt = 0; mt < 4; ++mt) { acc4[mt][0]=fz; acc4[mt][1]=fz; }
  {
    int tiles[2] = {2*w, 2*w+1};
    run_gemm<5,2>(xh, 168, a.Pn11, 8, tiles, 2, lane, acc4);
  }
  #pragma unroll
  for (int nt = 0; nt < 2; ++nt) {
    int col = (2*w + nt)*16 + m;
    #pragma unroll
    for (int mt = 0; mt < 4; ++mt)
      #pragma unroll
      for (int r = 0; r < 4; ++r) {
        int row = mt*16 + q*4 + r;
        ldsH[row*136 + col] = f2b(fmaxf(acc4[mt][nt][r], 0.f));
      }
  }
  __syncthreads();

  // ---- n1 out: Hn1 @ Pn12 + residual [xh,e] + b2 -> LN -> scatter ----
  f4v acc5[4][3];
  #pragma unroll
  for (int mt = 0; mt < 4; ++mt) { acc5[mt][0]=fz; acc5[mt][1]=fz; acc5[mt][2]=fz; }
  run_gemm<4,3>(ldsH, 136, a.Pn12, 9, tiles3, nt3, lane, acc5);

  float gc[3], bnc[3]; int colv[3]; bool cval[3];
  #pragma unroll
  for (int ti = 0; ti < 3; ++ti) {
    cval[ti] = false; colv[ti] = 0; gc[ti] = 0.f; bnc[ti] = 0.f;
    if (ti < nt3) {
      int col = tiles3[ti]*16 + m;
      colv[ti] = col;
      if (col < 130) {
        cval[ti] = true;
        float bias = a.n1_b2[col];
        gc[ti] = a.n1_g[col]; bnc[ti] = a.n1_bn[col];
        #pragma unroll
        for (int mt = 0; mt < 4; ++mt)
          #pragma unroll
          for (int r = 0; r < 4; ++r) {
            int row = mt*16 + q*4 + r;
            acc5[mt][ti][r] += bias + b2f(xh[row*168 + col]);
          }
      }
    }
  }
  {
    float sB[4][4], qB[4][4];
    #pragma unroll
    for (int mt = 0; mt < 4; ++mt)
      #pragma unroll
      for (int r = 0; r < 4; ++r) {
        float s = 0.f, ss = 0.f;
        #pragma unroll
        for (int ti = 0; ti < 3; ++ti)
          if (cval[ti]) { float v = acc5[mt][ti][r]; s += v; ss += v*v; }
        sB[mt][r] = s; qB[mt][r] = ss;
      }
    #pragma unroll
    for (int mask = 1; mask <= 8; mask <<= 1)
      #pragma unroll
      for (int mt = 0; mt < 4; ++mt)
        #pragma unroll
        for (int r = 0; r < 4; ++r) {
          sB[mt][r] += __shfl_xor(sB[mt][r], mask);
          qB[mt][r] += __shfl_xor(qB[mt][r], mask);
        }
    if (m == 0) {
      #pragma unroll
      for (int mt = 0; mt < 4; ++mt)
        #pragma unroll
        for (int r = 0; r < 4; ++r) {
          int row = mt*16 + q*4 + r;
          rowred[(row*4 + w)*2]     = sB[mt][r];
          rowred[(row*4 + w)*2 + 1] = qB[mt][r];
        }
    }
  }
  __syncthreads();
  if (tid < 64) {
    float s = 0.f, ss = 0.f;
    #pragma unroll
    for (int ww = 0; ww < 4; ++ww) { s += rowred[(tid*4+ww)*2]; ss += rowred[(tid*4+ww)*2+1]; }
    float mu = s * (1.f/130.f);
    float var = ss * (1.f/130.f) - mu*mu;
    float* mv = (float*)(ldsX + tid*168 + 160);
    mv[0] = mu; mv[1] = rsqrtf(var + 1e-5f);
  }
  __syncthreads();

  #pragma unroll
  for (int mt = 0; mt < 4; ++mt)
    #pragma unroll
    for (int r = 0; r < 4; ++r) {
      int row = mt*16 + q*4 + r;
      int seg = __shfl(segr, row);
      if (seg < 0) continue;
      const float* mv = (const float*)(ldsX + row*168 + 160);
      float mu = mv[0], rsg = mv[1];
      #pragma unroll
      for (int ti = 0; ti < 3; ++ti)
        if (cval[ti]) {
          float val = (acc5[mt][ti][r] - mu)*rsg*gc[ti] + bnc[ti];
          atomicAdd(&a.gsum[seg*130 + colv[ti]], val);
        }
    }
}

// ---------------- mesh-node kernel: scatter-mean + n2 FFN ----------------
struct BArgs {
  const float *gsum, *cnt;
  const float *Wr, *br, *W1, *b1, *W2, *b2, *g, *bn;
  float* out;
};

__global__ __launch_bounds__(128) void kB(BArgs b) {
  __shared__ float aggL[130];
  __shared__ float hidL[128];
  __shared__ float red[4];
  int j = threadIdx.x, seg = blockIdx.x;
  float inv = 1.0f / fmaxf(b.cnt[seg], 1.0f);
  for (int c = j; c < 130; c += 128) aggL[c] = b.gsum[seg*130 + c] * inv;
  __syncthreads();
  float resv = b.br[j];
  float hv   = b.b1[j];
  for (int k = 0; k < 130; ++k) {
    float av = aggL[k];
    resv += av * b.Wr[(128 + k)*128 + j];   // only rows 128..257 matter (nodes part = 0)
    hv   += av * b.W1[(128 + k)*128 + j];
  }
  hv = fmaxf(hv, 0.f);
  hidL[j] = hv;
  __syncthreads();
  float ov = b.b2[j];
  for (int k = 0; k < 128; ++k) ov += hidL[k] * b.W2[k*128 + j];
  float sv = resv + ov;
  float s = sv, ss = sv*sv;
  for (int off = 32; off > 0; off >>= 1) { s += __shfl_down(s, off); ss += __shfl_down(ss, off); }
  int wv = j >> 6;
  if ((j & 63) == 0) { red[wv*2] = s; red[wv*2+1] = ss; }
  __syncthreads();
  float S = red[0] + red[2], SS = red[1] + red[3];
  float mu = S * (1.f/128.f);
  float var = SS * (1.f/128.f) - mu*mu;
  float rsg = rsqrtf(var + 1e-5f);
  b.out[seg*128 + j] = (sv - mu)*rsg*b.g[j] + b.bn[j];
}

// ---------------- launch ----------------
extern "C" void kernel_launch(void* const* d_in, const int* in_sizes, int n_in,
                              void* d_out, int out_size, void* d_ws, size_t ws_size,
                              hipStream_t stream) {
  const float* x      = (const float*)d_in[0];
  const float* eattr  = (const float*)d_in[1];
  const int*   eidx   = (const int*)d_in[2];
  const float* enc_Wr = (const float*)d_in[4];
  const float* enc_br = (const float*)d_in[5];
  const float* enc_W1 = (const float*)d_in[6];
  const float* enc_b1 = (const float*)d_in[7];
  const float* enc_W2 = (const float*)d_in[8];
  const float* enc_b2 = (const float*)d_in[9];
  const float* enc_g  = (const float*)d_in[10];
  const float* enc_bn = (const float*)d_in[11];
  const float* em_Wr  = (const float*)d_in[12];
  const float* em_br  = (const float*)d_in[13];
  const float* em_W1  = (const float*)d_in[14];
  const float* em_b1  = (const float*)d_in[15];
  const float* em_W2  = (const float*)d_in[16];
  const float* em_b2  = (const float*)d_in[17];
  const float* em_g   = (const float*)d_in[18];
  const float* em_bn  = (const float*)d_in[19];
  const float* n1_W1  = (const float*)d_in[20];
  const float* n1_b1  = (const float*)d_in[21];
  const float* n1_W2  = (const float*)d_in[22];
  const float* n1_b2  = (const float*)d_in[23];
  const float* n1_g   = (const float*)d_in[24];
  const float* n1_bn  = (const float*)d_in[25];
  const float* n2_Wr  = (const float*)d_in[26];
  const float* n2_br  = (const float*)d_in[27];
  const float* n2_W1  = (const float*)d_in[28];
  const float* n2_b1  = (const float*)d_in[29];
  const float* n2_W2  = (const float*)d_in[30];
  const float* n2_b2  = (const float*)d_in[31];
  const float* n2_g   = (const float*)d_in[32];
  const float* n2_bn  = (const float*)d_in[33];

  short* wsP  = (short*)d_ws;
  float* gsum = (float*)((char*)d_ws + GSUM_BYTE_OFF);
  float* cnt  = (float*)((char*)d_ws + CNT_BYTE_OFF);

  hipMemsetAsync(gsum, 0, GSUM_BYTES + CNT_BYTES, stream);

  PArgs pa = { enc_Wr, enc_W1, enc_W2, em_Wr, em_W1, em_b1, em_br, n1_W1, n1_b1, n1_W2, wsP };
  kPack<<<71, 256, 0, stream>>>(pa);

  AArgs aa;
  aa.x = x; aa.eattr = eattr; aa.eidx = eidx;
  aa.enc_br = enc_br; aa.enc_b1 = enc_b1; aa.enc_b2 = enc_b2; aa.enc_g = enc_g; aa.enc_bn = enc_bn;
  aa.em_W2 = em_W2; aa.em_b2 = em_b2; aa.em_g = em_g; aa.em_bn = em_bn;
  aa.n1_b2 = n1_b2; aa.n1_g = n1_g; aa.n1_bn = n1_bn;
  aa.Penc1 = wsP + OFF_ENC1; aa.PencW2 = wsP + OFF_ENCW2;
  aa.Pem1 = wsP + OFF_EM1; aa.Pn11 = wsP + OFF_N11; aa.Pn12 = wsP + OFF_N12;
  aa.gsum = gsum; aa.cnt = cnt;
  kA<<<(EDGES + 63)/64, 256, 0, stream>>>(aa);

  BArgs ba = { gsum, cnt, n2_Wr, n2_br, n2_W1, n2_b1, n2_W2, n2_b2, n2_g, n2_bn, (float*)d_out };
  kB<<<NMESH, 128, 0, stream>>>(ba);
}

// Round 2
// 1352.409 us; speedup vs baseline: 1.1205x; 1.0544x over previous
//
#include <hip/hip_runtime.h>
#include <hip/hip_bf16.h>

#define EDGES   519840
#define NGRID   519840
#define NMESH   5882

typedef short s8v __attribute__((ext_vector_type(8)));
typedef float f4v __attribute__((ext_vector_type(4)));

// ---- ws layout ----
// packed weights (bf16 shorts), element offsets:
#define OFF_ENC1   0        // 8 ksteps * 16 ntiles * 64 * 8 = 65536 el ([Wr|W1] 256x256)
#define OFF_ENCW2  65536    // 4*8*64*8  = 16384 el (128x128)
#define OFF_EM1    81920    // 5*9*64*8  = 23040 el (160x144: W1eff|res cols, bias row k=130)
#define OFF_N11    104960   // 5*8*64*8  = 20480 el (160x128, bias row k=130)
#define OFF_N12    125440   // 4*9*64*8  = 18432 el (128x144)
#define PACK_EL    143872
#define GSUM_BYTE_OFF  (PACK_EL*2)            // 287744
#define GSUM_BYTES     (NMESH*130*4)          // 3058640
#define CNT_BYTE_OFF   (GSUM_BYTE_OFF + GSUM_BYTES)
#define CNT_BYTES      (NMESH*4)

__device__ __forceinline__ float b2f(short s) {
  unsigned int u = ((unsigned int)(unsigned short)s) << 16;
  float f; __builtin_memcpy(&f, &u, 4); return f;
}
__device__ __forceinline__ short f2b(float f) {
  __hip_bfloat16 h = __float2bfloat16(f);   // RNE
  short s; __builtin_memcpy(&s, &h, 2); return s;
}

// ---------------- weight pack kernel (fp32 -> bf16, MFMA B layout) ----------------
struct PArgs {
  const float *enc_Wr, *enc_W1, *enc_W2;
  const float *em_Wr, *em_W1, *em_b1, *em_br;
  const float *n1_W1, *n1_b1, *n1_W2;
  short* dst;
};

__global__ __launch_bounds__(256) void kPack(PArgs p) {
  int g = blockIdx.x * 256 + threadIdx.x;
  if (g >= 17984) return;
  short* dst = p.dst;
  if (g < 8192) {                       // enc combined [Wr|W1], K=256, NT=16
    int s = g >> 10; int rem = g & 1023; int t = rem >> 6; int l = rem & 63;
    int qq = l >> 4, n = (t << 4) + (l & 15);
    s8v v;
    #pragma unroll
    for (int j = 0; j < 8; ++j) {
      int k = s*32 + qq*8 + j;
      v[j] = (n < 128) ? f2b(p.enc_Wr[k*128 + n]) : f2b(p.enc_W1[k*128 + (n-128)]);
    }
    ((s8v*)(dst + OFF_ENC1))[g] = v;
  } else if (g < 10240) {               // enc_W2, K=128, NT=8
    int g2 = g - 8192;
    int s = g2 >> 9; int t = (g2 >> 6) & 7; int l = g2 & 63;
    int qq = l >> 4, n = (t << 4) + (l & 15);
    s8v v;
    #pragma unroll
    for (int j = 0; j < 8; ++j) { int k = s*32 + qq*8 + j; v[j] = f2b(p.enc_W2[k*128 + n]); }
    ((s8v*)(dst + OFF_ENCW2))[g2] = v;
  } else if (g < 13120) {               // em1: KP=160, NT=9 (cols 128..129 = residual Wr)
    int g3 = g - 10240;
    int s = g3 / 576; int rem = g3 - s*576; int t = rem >> 6; int l = rem & 63;
    int qq = l >> 4, n = (t << 4) + (l & 15);
    s8v v;
    #pragma unroll
    for (int j = 0; j < 8; ++j) {
      int k = s*32 + qq*8 + j;
      float val = 0.f;
      if (n < 128) {
        if (k < 128)        val = p.em_W1[k*128 + n];
        else if (k < 130)   val = p.em_W1[(128 + k)*128 + n];   // rows 256,257 (edge_attr)
        else if (k == 130)  val = p.em_b1[n];                   // bias fold (A col130 = 1)
      } else if (n < 130) {
        int h = n - 128;
        if (k < 128)        val = p.em_Wr[k*2 + h];
        else if (k < 130)   val = p.em_Wr[(128 + k)*2 + h];
        else if (k == 130)  val = p.em_br[h];
      }
      v[j] = f2b(val);
    }
    ((s8v*)(dst + OFF_EM1))[g3] = v;
  } else if (g < 15680) {               // n1_W1: KP=160, NT=8
    int g4 = g - 13120;
    int s = g4 >> 9; int t = (g4 >> 6) & 7; int l = g4 & 63;
    int qq = l >> 4, n = (t << 4) + (l & 15);
    s8v v;
    #pragma unroll
    for (int j = 0; j < 8; ++j) {
      int k = s*32 + qq*8 + j;
      float val = 0.f;
      if (k < 130)       val = p.n1_W1[k*128 + n];
      else if (k == 130) val = p.n1_b1[n];
      v[j] = f2b(val);
    }
    ((s8v*)(dst + OFF_N11))[g4] = v;
  } else {                              // n1_W2: K=128, NT=9 (N padded 130->144)
    int g5 = g - 15680;
    int s = g5 / 576; int rem = g5 - s*576; int t = rem >> 6; int l = rem & 63;
    int qq = l >> 4, n = (t << 4) + (l & 15);
    s8v v;
    #pragma unroll
    for (int j = 0; j < 8; ++j) {
      int k = s*32 + qq*8 + j;
      v[j] = (n < 130) ? f2b(p.n1_W2[k*130 + n]) : (short)0;
    }
    ((s8v*)(dst + OFF_N12))[g5] = v;
  }
}

// ---------------- generic MFMA tile loop ----------------
template<int KS, int MAXT>
__device__ __forceinline__ void run_gemm(const short* A, int strideA,
                                         const short* Bpack, int ntp,
                                         const int* tiles, int nt, int lane,
                                         f4v acc[][MAXT]) {
  const int m = lane & 15, qq = lane >> 4;
  const s8v* Bp = (const s8v*)Bpack;
  #pragma unroll
  for (int s = 0; s < KS; ++s) {
    s8v af[4];
    #pragma unroll
    for (int mt = 0; mt < 4; ++mt)
      af[mt] = *(const s8v*)(A + (mt*16 + m)*strideA + s*32 + qq*8);
    #pragma unroll
    for (int ti = 0; ti < MAXT; ++ti) {
      if (ti < nt) {
        s8v bf = Bp[(s*ntp + tiles[ti])*64 + lane];
        #pragma unroll
        for (int mt = 0; mt < 4; ++mt)
          acc[mt][ti] = __builtin_amdgcn_mfma_f32_16x16x32_bf16(af[mt], bf, acc[mt][ti], 0, 0, 0);
      }
    }
  }
}

// ---------------- fused per-edge kernel ----------------
struct AArgs {
  const float *x, *eattr;
  const int   *eidx;
  const float *enc_br, *enc_b1, *enc_b2, *enc_g, *enc_bn;
  const float *em_W2, *em_b2, *em_g, *em_bn;
  const float *n1_b2, *n1_g, *n1_bn;
  const short *Penc1, *PencW2, *Pem1, *Pn11, *Pn12;
  float *gsum, *cnt;
};

// LDS budget: 21504 (ldsX) + 17408 (ldsH) + 2048 (ldsD) = 40960 B.
// launch_bounds(256,3): 3 waves/EU -> unified VGPR cap ~170 (kernel needs ~160,
// spill-free). (256,4) capped at 128 and spilled ~30 regs -> +700MB HBM traffic.
__global__ __launch_bounds__(256, 3) void kA(AArgs a) {
  __shared__ __align__(16) short ldsX[64*168];  // X half-tile [64][136]; later xh [64][168]
                                                // per-row hole cols 160..163: {mu, rsig}
  __shared__ __align__(16) short ldsH[64*136];  // hidden buffer (all FFN hiddens)
  __shared__ __align__(16) float ldsD[512];     // rowred[512]  OR  vbuf[0..127]+part2[128..383]

  float* const rowred = ldsD;
  float* const vbuf   = ldsD;
  float* const part2  = ldsD + 128;

  const int tid  = threadIdx.x;
  const int lane = tid & 63;
  const int w    = tid >> 6;
  const int m    = lane & 15;
  const int q    = lane >> 4;
  const long row0 = (long)blockIdx.x * 64;

  // per-lane segment id for edge (row0+lane); -1 when out of range (kept in reg, bcast via shfl)
  int segr = -1;
  if (row0 + lane < EDGES) segr = a.eidx[EDGES + row0 + lane] - NGRID;

  float ea0 = 0.f, ea1 = 0.f;
  if (tid < 64 && segr >= 0) {
    atomicAdd(&a.cnt[segr], 1.0f);
    ea0 = a.eattr[(row0 + tid)*2];
    ea1 = a.eattr[(row0 + tid)*2 + 1];
  }

  f4v acc1[4][4];
  const f4v fz = {0.f,0.f,0.f,0.f};
  #pragma unroll
  for (int mt = 0; mt < 4; ++mt)
    #pragma unroll
    for (int nt = 0; nt < 4; ++nt) acc1[mt][nt] = fz;

  // wave w owns R-tiles {2w,2w+1} (cols 32w..32w+31) and H-tiles {8+2w,9+2w}:
  // residual stays in registers (same C-fragment mapping as stage-2 output tiles).
  const int tiles1[4] = {2*w, 2*w+1, 8+2*w, 9+2*w};

  // ---- stage 1: [R | Hpre] = X @ [enc_Wr | enc_W1], K=256 split in two 128-col halves ----
  #pragma unroll
  for (int half = 0; half < 2; ++half) {
    if (half) __syncthreads();          // half-0 LDS reads done before restage
    for (int i = tid; i < 64*16; i += 256) {
      int r = i >> 4, c = (i & 15) << 3;
      s8v v = {0,0,0,0,0,0,0,0};
      if (row0 + r < EDGES) {
        const float* xr = a.x + (row0 + r)*256 + half*128 + c;
        float4 u0 = *(const float4*)(xr);
        float4 u1 = *(const float4*)(xr + 4);
        v[0]=f2b(u0.x); v[1]=f2b(u0.y); v[2]=f2b(u0.z); v[3]=f2b(u0.w);
        v[4]=f2b(u1.x); v[5]=f2b(u1.y); v[6]=f2b(u1.z); v[7]=f2b(u1.w);
      }
      *(s8v*)(ldsX + r*136 + c) = v;
    }
    __syncthreads();
    run_gemm<4,4>(ldsX, 136, a.Penc1 + half*(4*16*64*8), 16, tiles1, 4, lane, acc1);
  }

  // H tiles -> ldsH with ReLU + b1 (wave w covers cols 32w..32w+31)
  #pragma unroll
  for (int ti = 2; ti < 4; ++ti) {
    int hc = (tiles1[ti] - 8)*16 + m;
    float bias = a.enc_b1[hc];
    #pragma unroll
    for (int mt = 0; mt < 4; ++mt)
      #pragma unroll
      for (int r = 0; r < 4; ++r)
        ldsH[(mt*16 + q*4 + r)*136 + hc] = f2b(fmaxf(acc1[mt][ti][r] + bias, 0.f));
  }
  __syncthreads();

  // ---- stage 2: D2 = H1 @ enc_W2 ; S = R + D2 + br + b2 (all in regs) ----
  f4v acc2[4][2];
  #pragma unroll
  for (int mt = 0; mt < 4; ++mt) { acc2[mt][0] = fz; acc2[mt][1] = fz; }
  {
    int tiles[2] = {2*w, 2*w+1};
    run_gemm<4,2>(ldsH, 136, a.PencW2, 8, tiles, 2, lane, acc2);
  }
  #pragma unroll
  for (int nt = 0; nt < 2; ++nt) {
    int col = (2*w + nt)*16 + m;
    float bb = a.enc_br[col] + a.enc_b2[col];
    #pragma unroll
    for (int mt = 0; mt < 4; ++mt)
      #pragma unroll
      for (int r = 0; r < 4; ++r)
        acc2[mt][nt][r] += acc1[mt][nt][r] + bb;
  }

  // ---- LN1 over 128 dims ----
  {
    float sA[4][4], qA[4][4];
    #pragma unroll
    for (int mt = 0; mt < 4; ++mt)
      #pragma unroll
      for (int r = 0; r < 4; ++r) {
        float s = 0.f, ss = 0.f;
        #pragma unroll
        for (int nt = 0; nt < 2; ++nt) { float v = acc2[mt][nt][r]; s += v; ss += v*v; }
        sA[mt][r] = s; qA[mt][r] = ss;
      }
    #pragma unroll
    for (int mask = 1; mask <= 8; mask <<= 1)
      #pragma unroll
      for (int mt = 0; mt < 4; ++mt)
        #pragma unroll
        for (int r = 0; r < 4; ++r) {
          sA[mt][r] += __shfl_xor(sA[mt][r], mask);
          qA[mt][r] += __shfl_xor(qA[mt][r], mask);
        }
    if (m == 0) {
      #pragma unroll
      for (int mt = 0; mt < 4; ++mt)
        #pragma unroll
        for (int r = 0; r < 4; ++r) {
          int row = mt*16 + q*4 + r;
          rowred[(row*4 + w)*2]     = sA[mt][r];
          rowred[(row*4 + w)*2 + 1] = qA[mt][r];
        }
    }
  }
  __syncthreads();
  if (tid < 64) {
    float s = 0.f, ss = 0.f;
    #pragma unroll
    for (int ww = 0; ww < 4; ++ww) { s += rowred[(tid*4+ww)*2]; ss += rowred[(tid*4+ww)*2+1]; }
    float mu = s * (1.f/128.f);
    float var = ss * (1.f/128.f) - mu*mu;
    float* mv = (float*)(ldsX + tid*168 + 160);
    mv[0] = mu; mv[1] = rsqrtf(var + 1e-5f);
  }
  __syncthreads();

  // write x_hat (bf16) into ldsX as [64][168] + [ea | 1.0 | zeros] extension to K=160
  short* const xh = ldsX;
  #pragma unroll
  for (int nt = 0; nt < 2; ++nt) {
    int col = (2*w + nt)*16 + m;
    float gv = a.enc_g[col], bv = a.enc_bn[col];
    #pragma unroll
    for (int mt = 0; mt < 4; ++mt)
      #pragma unroll
      for (int r = 0; r < 4; ++r) {
        int row = mt*16 + q*4 + r;
        const float* mv = (const float*)(ldsX + row*168 + 160);
        xh[row*168 + col] = f2b((acc2[mt][nt][r] - mv[0])*mv[1]*gv + bv);
      }
  }
  if (tid < 64) {
    xh[tid*168 + 128] = f2b(ea0);
    xh[tid*168 + 129] = f2b(ea1);
    xh[tid*168 + 130] = (short)0x3f80;   // bf16 1.0 (bias fold column)
    #pragma unroll
    for (int c = 131; c < 160; ++c) xh[tid*168 + c] = 0;
  }
  __syncthreads();

  // ---- em: hidden (+ residual cols 128..129) = xh160 @ Pem1 ----
  int tiles3[3] = {w, w+4, w+8};
  const int nt3 = (w == 0) ? 3 : 2;
  f4v acc3[4][3];
  #pragma unroll
  for (int mt = 0; mt < 4; ++mt) { acc3[mt][0]=fz; acc3[mt][1]=fz; acc3[mt][2]=fz; }
  run_gemm<5,3>(xh, 168, a.Pem1, 9, tiles3, nt3, lane, acc3);
  #pragma unroll
  for (int ti = 0; ti < 3; ++ti) {
    if (ti < nt3) {
      int col = tiles3[ti]*16 + m;
      if (col < 128) {
        #pragma unroll
        for (int mt = 0; mt < 4; ++mt)
          #pragma unroll
          for (int r = 0; r < 4; ++r) {
            int row = mt*16 + q*4 + r;
            ldsH[row*136 + col] = f2b(fmaxf(acc3[mt][ti][r], 0.f));
          }
      } else if (col < 130) {
        #pragma unroll
        for (int mt = 0; mt < 4; ++mt)
          #pragma unroll
          for (int r = 0; r < 4; ++r) {
            int row = mt*16 + q*4 + r;
            vbuf[row*2 + (col - 128)] = acc3[mt][ti][r];   // residual (br folded)
          }
      }
    }
  }
  __syncthreads();

  // em second projection (128 -> 2) on VALU, fp32 weights
  {
    int r = tid >> 2, p = tid & 3, h = p & 1, kh = p >> 1;
    float s2 = 0.f;
    const short* hb = ldsH + r*136 + kh*64;
    const float* w2 = a.em_W2 + kh*128 + h;   // em_W2[(kh*64+k)*2 + h]
    #pragma unroll 8
    for (int k = 0; k < 64; ++k) s2 += b2f(hb[k]) * w2[2*k];
    part2[tid] = s2;
  }
  __syncthreads();
  if (tid < 128) {
    int r = tid >> 1, h = tid & 1;
    vbuf[tid] = vbuf[tid] + part2[r*4 + h] + part2[r*4 + 2 + h] + a.em_b2[h];
  }
  __syncthreads();
  if (tid < 64) {    // LN over 2 dims, closed form; e = ... + edge_attr
    float v0 = vbuf[2*tid], v1 = vbuf[2*tid+1];
    float d = 0.5f*(v0 - v1);
    float rsg = rsqrtf(d*d + 1e-5f);
    float e0 =  d*rsg*a.em_g[0] + a.em_bn[0] + ea0;
    float e1 = -d*rsg*a.em_g[1] + a.em_bn[1] + ea1;
    xh[tid*168 + 128] = f2b(e0);
    xh[tid*168 + 129] = f2b(e1);
  }
  __syncthreads();

  // ---- n1 hidden: xh160 @ Pn11 ----
  f4v acc4[4][2];
  #pragma unroll
  for (int mt = 0; mt < 4; ++mt) { acc4[mt][0]=fz; acc4[mt][1]=fz; }
  {
    int tiles[2] = {2*w, 2*w+1};
    run_gemm<5,2>(xh, 168, a.Pn11, 8, tiles, 2, lane, acc4);
  }
  #pragma unroll
  for (int nt = 0; nt < 2; ++nt) {
    int col = (2*w + nt)*16 + m;
    #pragma unroll
    for (int mt = 0; mt < 4; ++mt)
      #pragma unroll
      for (int r = 0; r < 4; ++r) {
        int row = mt*16 + q*4 + r;
        ldsH[row*136 + col] = f2b(fmaxf(acc4[mt][nt][r], 0.f));
      }
  }
  __syncthreads();

  // ---- n1 out: Hn1 @ Pn12 + residual [xh,e] + b2 -> LN -> scatter ----
  f4v acc5[4][3];
  #pragma unroll
  for (int mt = 0; mt < 4; ++mt) { acc5[mt][0]=fz; acc5[mt][1]=fz; acc5[mt][2]=fz; }
  run_gemm<4,3>(ldsH, 136, a.Pn12, 9, tiles3, nt3, lane, acc5);

  float gc[3], bnc[3]; int colv[3]; bool cval[3];
  #pragma unroll
  for (int ti = 0; ti < 3; ++ti) {
    cval[ti] = false; colv[ti] = 0; gc[ti] = 0.f; bnc[ti] = 0.f;
    if (ti < nt3) {
      int col = tiles3[ti]*16 + m;
      colv[ti] = col;
      if (col < 130) {
        cval[ti] = true;
        float bias = a.n1_b2[col];
        gc[ti] = a.n1_g[col]; bnc[ti] = a.n1_bn[col];
        #pragma unroll
        for (int mt = 0; mt < 4; ++mt)
          #pragma unroll
          for (int r = 0; r < 4; ++r) {
            int row = mt*16 + q*4 + r;
            acc5[mt][ti][r] += bias + b2f(xh[row*168 + col]);
          }
      }
    }
  }
  {
    float sB[4][4], qB[4][4];
    #pragma unroll
    for (int mt = 0; mt < 4; ++mt)
      #pragma unroll
      for (int r = 0; r < 4; ++r) {
        float s = 0.f, ss = 0.f;
        #pragma unroll
        for (int ti = 0; ti < 3; ++ti)
          if (cval[ti]) { float v = acc5[mt][ti][r]; s += v; ss += v*v; }
        sB[mt][r] = s; qB[mt][r] = ss;
      }
    #pragma unroll
    for (int mask = 1; mask <= 8; mask <<= 1)
      #pragma unroll
      for (int mt = 0; mt < 4; ++mt)
        #pragma unroll
        for (int r = 0; r < 4; ++r) {
          sB[mt][r] += __shfl_xor(sB[mt][r], mask);
          qB[mt][r] += __shfl_xor(qB[mt][r], mask);
        }
    if (m == 0) {
      #pragma unroll
      for (int mt = 0; mt < 4; ++mt)
        #pragma unroll
        for (int r = 0; r < 4; ++r) {
          int row = mt*16 + q*4 + r;
          rowred[(row*4 + w)*2]     = sB[mt][r];
          rowred[(row*4 + w)*2 + 1] = qB[mt][r];
        }
    }
  }
  __syncthreads();
  if (tid < 64) {
    float s = 0.f, ss = 0.f;
    #pragma unroll
    for (int ww = 0; ww < 4; ++ww) { s += rowred[(tid*4+ww)*2]; ss += rowred[(tid*4+ww)*2+1]; }
    float mu = s * (1.f/130.f);
    float var = ss * (1.f/130.f) - mu*mu;
    float* mv = (float*)(ldsX + tid*168 + 160);
    mv[0] = mu; mv[1] = rsqrtf(var + 1e-5f);
  }
  __syncthreads();

  #pragma unroll
  for (int mt = 0; mt < 4; ++mt)
    #pragma unroll
    for (int r = 0; r < 4; ++r) {
      int row = mt*16 + q*4 + r;
      int seg = __shfl(segr, row);
      if (seg < 0) continue;
      const float* mv = (const float*)(ldsX + row*168 + 160);
      float mu = mv[0], rsg = mv[1];
      #pragma unroll
      for (int ti = 0; ti < 3; ++ti)
        if (cval[ti]) {
          float val = (acc5[mt][ti][r] - mu)*rsg*gc[ti] + bnc[ti];
          atomicAdd(&a.gsum[seg*130 + colv[ti]], val);
        }
    }
}

// ---------------- mesh-node kernel: scatter-mean + n2 FFN ----------------
struct BArgs {
  const float *gsum, *cnt;
  const float *Wr, *br, *W1, *b1, *W2, *b2, *g, *bn;
  float* out;
};

__global__ __launch_bounds__(128) void kB(BArgs b) {
  __shared__ float aggL[130];
  __shared__ float hidL[128];
  __shared__ float red[4];
  int j = threadIdx.x, seg = blockIdx.x;
  float inv = 1.0f / fmaxf(b.cnt[seg], 1.0f);
  for (int c = j; c < 130; c += 128) aggL[c] = b.gsum[seg*130 + c] * inv;
  __syncthreads();
  float resv = b.br[j];
  float hv   = b.b1[j];
  for (int k = 0; k < 130; ++k) {
    float av = aggL[k];
    resv += av * b.Wr[(128 + k)*128 + j];   // only rows 128..257 matter (nodes part = 0)
    hv   += av * b.W1[(128 + k)*128 + j];
  }
  hv = fmaxf(hv, 0.f);
  hidL[j] = hv;
  __syncthreads();
  float ov = b.b2[j];
  for (int k = 0; k < 128; ++k) ov += hidL[k] * b.W2[k*128 + j];
  float sv = resv + ov;
  float s = sv, ss = sv*sv;
  for (int off = 32; off > 0; off >>= 1) { s += __shfl_down(s, off); ss += __shfl_down(ss, off); }
  int wv = j >> 6;
  if ((j & 63) == 0) { red[wv*2] = s; red[wv*2+1] = ss; }
  __syncthreads();
  float S = red[0] + red[2], SS = red[1] + red[3];
  float mu = S * (1.f/128.f);
  float var = SS * (1.f/128.f) - mu*mu;
  float rsg = rsqrtf(var + 1e-5f);
  b.out[seg*128 + j] = (sv - mu)*rsg*b.g[j] + b.bn[j];
}

// ---------------- launch ----------------
extern "C" void kernel_launch(void* const* d_in, const int* in_sizes, int n_in,
                              void* d_out, int out_size, void* d_ws, size_t ws_size,
                              hipStream_t stream) {
  const float* x      = (const float*)d_in[0];
  const float* eattr  = (const float*)d_in[1];
  const int*   eidx   = (const int*)d_in[2];
  const float* enc_Wr = (const float*)d_in[4];
  const float* enc_br = (const float*)d_in[5];
  const float* enc_W1 = (const float*)d_in[6];
  const float* enc_b1 = (const float*)d_in[7];
  const float* enc_W2 = (const float*)d_in[8];
  const float* enc_b2 = (const float*)d_in[9];
  const float* enc_g  = (const float*)d_in[10];
  const float* enc_bn = (const float*)d_in[11];
  const float* em_Wr  = (const float*)d_in[12];
  const float* em_br  = (const float*)d_in[13];
  const float* em_W1  = (const float*)d_in[14];
  const float* em_b1  = (const float*)d_in[15];
  const float* em_W2  = (const float*)d_in[16];
  const float* em_b2  = (const float*)d_in[17];
  const float* em_g   = (const float*)d_in[18];
  const float* em_bn  = (const float*)d_in[19];
  const float* n1_W1  = (const float*)d_in[20];
  const float* n1_b1  = (const float*)d_in[21];
  const float* n1_W2  = (const float*)d_in[22];
  const float* n1_b2  = (const float*)d_in[23];
  const float* n1_g   = (const float*)d_in[24];
  const float* n1_bn  = (const float*)d_in[25];
  const float* n2_Wr  = (const float*)d_in[26];
  const float* n2_br  = (const float*)d_in[27];
  const float* n2_W1  = (const float*)d_in[28];
  const float* n2_b1  = (const float*)d_in[29];
  const float* n2_W2  = (const float*)d_in[30];
  const float* n2_b2  = (const float*)d_in[31];
  const float* n2_g   = (const float*)d_in[32];
  const float* n2_bn  = (const float*)d_in[33];

  short* wsP  = (short*)d_ws;
  float* gsum = (float*)((char*)d_ws + GSUM_BYTE_OFF);
  float* cnt  = (float*)((char*)d_ws + CNT_BYTE_OFF);

  hipMemsetAsync(gsum, 0, GSUM_BYTES + CNT_BYTES, stream);

  PArgs pa = { enc_Wr, enc_W1, enc_W2, em_Wr, em_W1, em_b1, em_br, n1_W1, n1_b1, n1_W2, wsP };
  kPack<<<71, 256, 0, stream>>>(pa);

  AArgs aa;
  aa.x = x; aa.eattr = eattr; aa.eidx = eidx;
  aa.enc_br = enc_br; aa.enc_b1 = enc_b1; aa.enc_b2 = enc_b2; aa.enc_g = enc_g; aa.enc_bn = enc_bn;
  aa.em_W2 = em_W2; aa.em_b2 = em_b2; aa.em_g = em_g; aa.em_bn = em_bn;
  aa.n1_b2 = n1_b2; aa.n1_g = n1_g; aa.n1_bn = n1_bn;
  aa.Penc1 = wsP + OFF_ENC1; aa.PencW2 = wsP + OFF_ENCW2;
  aa.Pem1 = wsP + OFF_EM1; aa.Pn11 = wsP + OFF_N11; aa.Pn12 = wsP + OFF_N12;
  aa.gsum = gsum; aa.cnt = cnt;
  kA<<<(EDGES + 63)/64, 256, 0, stream>>>(aa);

  BArgs ba = { gsum, cnt, n2_Wr, n2_br, n2_W1, n2_b1, n2_W2, n2_b2, n2_g, n2_bn, (float*)d_out };
  kB<<<NMESH, 128, 0, stream>>>(ba);
}